// Round 12
// baseline (549.599 us; speedup 1.0000x reference)
//
#include <hip/hip_runtime.h>
#include <stdint.h>

#define NEG_SLOPE 0.2f
#define BN_EPS 1e-5f

typedef __attribute__((ext_vector_type(8))) short bf16x8;
typedef __attribute__((ext_vector_type(4))) float f32x4;

// ---------------- bf16 helpers ----------------
__device__ __forceinline__ float bf2f(unsigned short u) {
  union { unsigned int i; float f; } v; v.i = ((unsigned int)u) << 16; return v.f;
}
__device__ __forceinline__ float asf(unsigned int u) {
  union { unsigned int i; float f; } v; v.i = u; return v.f;
}
__device__ __forceinline__ unsigned short f2bf(float f) {
  union { float f; unsigned int i; } v; v.f = f;
  unsigned int i = v.i;
  return (unsigned short)((i + 0x7fffu + ((i >> 16) & 1u)) >> 16);  // RNE
}
__device__ __forceinline__ float loadF(const void* p, long long i, int f32) {
  return f32 ? ((const float*)p)[i] : bf2f(((const unsigned short*)p)[i]);
}
__device__ __forceinline__ int edge_at(const void* ei, long long idx, int is64) {
  return is64 ? (int)((const long long*)ei)[idx] : ((const int*)ei)[idx];
}

// ---------------- W preprocessing + inline dtype detection ----------------
// Each block detects dtype locally (LDS), block 0 publishes flags for later kernels.
// WTx [272 rows][64 k] bf16: rows 0..255 = W^T; 256..259 = Ws[h]; 260..263 = Wd[h]; 264..271 = 0.
__global__ __launch_bounds__(256) void wtrans_kernel(
    const unsigned short* __restrict__ x, const int* __restrict__ ei32,
    const void* __restrict__ W0, const void* __restrict__ as0, const void* __restrict__ ad0,
    const void* __restrict__ W1, const void* __restrict__ as1, const void* __restrict__ ad1,
    int* __restrict__ flags,
    unsigned short* __restrict__ WTx0, unsigned short* __restrict__ WTx1) {
  __shared__ int wild, oddnz;
  __shared__ unsigned short Wl[64 * 258];
  int t = threadIdx.x;
  if (t == 0) { wild = 0; oddnz = 0; }
  __syncthreads();
  {
    int lw = 0, lo = 0;
    for (int i = t; i < 4096; i += 256) {
      unsigned short u = x[i];
      int ex = (u >> 7) & 0xFF;
      if (ex >= 0x86) lw++;               // impossible exponent for N(0,1) bf16
      if (ei32[2 * i + 1] != 0) lo++;     // int64 high words all zero
    }
    if (lw) atomicAdd(&wild, lw);
    if (lo) atomicAdd(&oddnz, lo);
  }
  __syncthreads();
  int f32 = (wild > 64) ? 1 : 0;
  if (blockIdx.x == 0 && t == 0) { flags[0] = f32; flags[1] = (oddnz == 0) ? 1 : 0; }

  const void* W = blockIdx.x ? W1 : W0;
  const void* asrc = blockIdx.x ? as1 : as0;
  const void* adst = blockIdx.x ? ad1 : ad0;
  unsigned short* WTx = blockIdx.x ? WTx1 : WTx0;
  for (int i = t; i < 64 * 256; i += 256) {
    int k = i >> 8, c = i & 255;
    Wl[k * 258 + c] = f32 ? f2bf(((const float*)W)[i]) : ((const unsigned short*)W)[i];
  }
  __syncthreads();
  {
    int c = t;
    #pragma unroll
    for (int k8 = 0; k8 < 64; k8 += 8) {
      unsigned int p0 = (unsigned int)Wl[(k8 + 0) * 258 + c] | ((unsigned int)Wl[(k8 + 1) * 258 + c] << 16);
      unsigned int p1 = (unsigned int)Wl[(k8 + 2) * 258 + c] | ((unsigned int)Wl[(k8 + 3) * 258 + c] << 16);
      unsigned int p2 = (unsigned int)Wl[(k8 + 4) * 258 + c] | ((unsigned int)Wl[(k8 + 5) * 258 + c] << 16);
      unsigned int p3 = (unsigned int)Wl[(k8 + 6) * 258 + c] | ((unsigned int)Wl[(k8 + 7) * 258 + c] << 16);
      uint4 pk; pk.x = p0; pk.y = p1; pk.z = p2; pk.w = p3;
      *(uint4*)&WTx[c * 64 + k8] = pk;
    }
  }
  for (int idx = t; idx < 512; idx += 256) {
    int r = idx >> 6;
    int k = idx & 63;
    int h = r & 3;
    const void* av = (r >> 2) ? adst : asrc;
    float acc = 0.f;
    #pragma unroll 8
    for (int c = 0; c < 64; c++)
      acc += bf2f(Wl[k * 258 + h * 64 + c]) * loadF(av, h * 64 + c, f32);
    WTx[(256 + r) * 64 + k] = f2bf(acc);
  }
  for (int idx = t; idx < 512; idx += 256) WTx[264 * 64 + idx] = 0;
}

// ---------------- CSR build ----------------
__global__ __launch_bounds__(256) void hist_kernel(const void* __restrict__ ei, int E, int N,
                                                   const int* __restrict__ flags,
                                                   int* __restrict__ deg) {
  int e = blockIdx.x * 256 + threadIdx.x;
  if (e >= E) return;
  int is64 = flags[1];
  int d = edge_at(ei, (long long)E + e, is64);
  d = (d < 0 || d >= N) ? 0 : d;
  atomicAdd(&deg[d], 1);
}

// single-block scan over deg: offsets[0..N], cursor[i] = offsets[i] (scatter's running slot)
__global__ __launch_bounds__(1024) void scan_kernel(const int* __restrict__ deg,
                                                    int* __restrict__ offsets,
                                                    int* __restrict__ cursor, int N) {
  __shared__ int wsum[16];
  int t = threadIdx.x;
  int lane = t & 63;
  int wid = t >> 6;
  int C = (N + 1023) / 1024;          // chunk per thread
  int b0 = t * C;
  // pass 1: chunk sums
  int s = 0;
  for (int i = 0; i < C; i++) {
    int idx = b0 + i;
    if (idx < N) s += deg[idx];
  }
  // wave inclusive scan of chunk sums
  int sc = s;
  #pragma unroll
  for (int o = 1; o < 64; o <<= 1) {
    int u = __shfl_up(sc, o);
    if (lane >= o) sc += u;
  }
  if (lane == 63) wsum[wid] = sc;
  __syncthreads();
  int wbase = 0;
  #pragma unroll
  for (int w = 0; w < 16; w++) if (w < wid) wbase += wsum[w];
  int base = wbase + sc - s;          // exclusive prefix of this thread's chunk
  // pass 2: write prefix
  if (t == 0) offsets[0] = 0;
  int run = base;
  for (int i = 0; i < C; i++) {
    int idx = b0 + i;
    if (idx < N) {
      cursor[idx] = run;              // scatter slot start
      run += deg[idx];
      offsets[idx + 1] = run;
    }
  }
}

__global__ __launch_bounds__(256) void scatter_kernel(
    const void* __restrict__ ei, int E, int N, const int* __restrict__ flags,
    int* __restrict__ cursor, int* __restrict__ csr_src) {
  int e = blockIdx.x * 256 + threadIdx.x;
  if (e >= E) return;
  int is64 = flags[1];
  int s = edge_at(ei, e, is64);
  int d = edge_at(ei, (long long)E + e, is64);
  s = (s < 0 || s >= N) ? 0 : s;
  d = (d < 0 || d >= N) ? 0 : d;
  int pos = atomicAdd(&cursor[d], 1);
  csr_src[pos] = s;
}

// ---------------- MFMA GEMM: xh = x @ W (bf16) + als/ald tile; optional fused BN ----------------
// 256 rows per block (4 row-tiles share one WTx staging). mode 1: BN+ReLU fused A-load.
__global__ __launch_bounds__(256, 3) void gemm_mfma(
    const void* __restrict__ x, const unsigned short* __restrict__ WTx,
    const int* __restrict__ flags, int mode,
    const float* __restrict__ gsum, const float* __restrict__ gsq,
    const void* __restrict__ gamma, const void* __restrict__ beta,
    unsigned short* __restrict__ xh, float* __restrict__ als, float* __restrict__ ald,
    int N) {
  __shared__ unsigned short WTs[272 * 68];    // 36 KB staged weights
  __shared__ unsigned short RP[4][16 * 68];   // per-wave repack chunk (8.5 KB)
  __shared__ float bnsc[64], bnsh[64];
  int f32 = flags[0];
  int t = threadIdx.x;
  for (int i = t; i < 272 * 8; i += 256) {
    int c = i >> 3, g = i & 7;
    uint4 v = ((const uint4*)WTx)[i];
    *(uint4*)&WTs[c * 68 + g * 8] = v;
  }
  if (mode == 1 && t < 64) {
    float mu = gsum[t] / (float)N;
    float var = fmaxf(gsq[t] / (float)N - mu * mu, 0.f);
    float sc = loadF(gamma, t, f32) * rsqrtf(var + BN_EPS);
    bnsc[t] = sc;
    bnsh[t] = loadF(beta, t, f32) - mu * sc;
  }
  __syncthreads();

  int wave = t >> 6, lane = t & 63;
  int q = lane >> 4, r16 = lane & 15;
  unsigned short* rp = RP[wave];

  for (int rb = 0; rb < 4; rb++) {
    int m0 = blockIdx.x * 256 + rb * 64 + wave * 16;
    if (m0 >= N) break;
    int row = m0 + r16;
    int rowc = row < N ? row : N - 1;

    bf16x8 a0, a1;
    if (mode == 1) {
      const float* xp = (const float*)x + (size_t)rowc * 64 + q * 8;
      float va[8], vb[8];
      *(float4*)&va[0] = ((const float4*)xp)[0];
      *(float4*)&va[4] = ((const float4*)xp)[1];
      *(float4*)&vb[0] = ((const float4*)(xp + 32))[0];
      *(float4*)&vb[4] = ((const float4*)(xp + 32))[1];
      int k0 = q * 8;
      #pragma unroll
      for (int jj = 0; jj < 8; jj++) {
        float v = fmaxf(va[jj] * bnsc[k0 + jj] + bnsh[k0 + jj], 0.f);
        float w = fmaxf(vb[jj] * bnsc[k0 + 32 + jj] + bnsh[k0 + 32 + jj], 0.f);
        a0[jj] = (short)f2bf(v);
        a1[jj] = (short)f2bf(w);
      }
    } else if (f32) {
      const float* xp = (const float*)x + (size_t)rowc * 64 + q * 8;
      float va[8], vb[8];
      *(float4*)&va[0] = ((const float4*)xp)[0];
      *(float4*)&va[4] = ((const float4*)xp)[1];
      *(float4*)&vb[0] = ((const float4*)(xp + 32))[0];
      *(float4*)&vb[4] = ((const float4*)(xp + 32))[1];
      #pragma unroll
      for (int jj = 0; jj < 8; jj++) {
        a0[jj] = (short)f2bf(va[jj]);
        a1[jj] = (short)f2bf(vb[jj]);
      }
    } else {
      const unsigned short* xp = (const unsigned short*)x + (size_t)rowc * 64 + q * 8;
      a0 = *(const bf16x8*)xp;
      a1 = *(const bf16x8*)(xp + 32);
    }

    f32x4 acc[17];
    #pragma unroll
    for (int tt = 0; tt < 17; tt++) acc[tt] = (f32x4){0.f, 0.f, 0.f, 0.f};
    #pragma unroll
    for (int tt = 0; tt < 17; tt++) {
      int c = tt * 16 + r16;
      bf16x8 b0 = *(const bf16x8*)&WTs[c * 68 + q * 8];
      bf16x8 b1 = *(const bf16x8*)&WTs[c * 68 + 32 + q * 8];
      acc[tt] = __builtin_amdgcn_mfma_f32_16x16x32_bf16(a0, b0, acc[tt], 0, 0, 0);
      acc[tt] = __builtin_amdgcn_mfma_f32_16x16x32_bf16(a1, b1, acc[tt], 0, 0, 0);
    }

    // epilogue 1: als/ald from tile 16
    {
      int obase = m0 + q * 4;
      #pragma unroll
      for (int rr = 0; rr < 4; rr++) {
        int orow = obase + rr;
        if (orow < N) {
          if (r16 < 4) als[orow * 4 + r16] = acc[16][rr];
          else if (r16 < 8) ald[orow * 4 + (r16 - 4)] = acc[16][rr];
        }
      }
    }
    // epilogue 2: 4 chunked passes, per-wave LDS repack (wave-internal, no barrier)
    #pragma unroll
    for (int g4 = 0; g4 < 4; g4++) {
      #pragma unroll
      for (int tt2 = 0; tt2 < 4; tt2++) {
        int tile = g4 * 4 + tt2;
        #pragma unroll
        for (int rr = 0; rr < 4; rr++)
          rp[(q * 4 + rr) * 68 + tt2 * 16 + r16] = f2bf(acc[tile][rr]);
      }
      #pragma unroll
      for (int i = 0; i < 2; i++) {
        int g = i * 64 + lane;
        int r = g >> 3;
        int grp = g & 7;
        uint4 v = *(const uint4*)&rp[r * 68 + grp * 8];
        int orow = m0 + r;
        if (orow < N) ((uint4*)xh)[(size_t)orow * 32 + g4 * 8 + grp] = v;
      }
    }
  }
}

// ---------------- per-dst-node softmax aggregation ----------------
// One node per wave (one-shot frame). Half-wave edge pairing; 8 edges per unrolled iter.
__global__ __launch_bounds__(256) void agg_kernel(
    const unsigned short* __restrict__ xh,
    const float* __restrict__ als, const float* __restrict__ ald,
    const int* __restrict__ offsets, const int* __restrict__ csr_src,
    const void* __restrict__ bias, const int* __restrict__ flags,
    float* __restrict__ y, int N) {
  int lane = threadIdx.x & 63;
  int wid = threadIdx.x >> 6;
  int n = blockIdx.x * 4 + wid;
  if (n >= N) return;
  int half = lane >> 5;     // 0: even slots + self, 1: odd slots
  int hl = lane & 31;       // channels 8*hl .. 8*hl+7
  int h = hl >> 3;          // head
  const uint4* xv = (const uint4*)xh;
  float ad = ald[n * 4 + h];
  float acc0 = 0.f, acc1 = 0.f, acc2 = 0.f, acc3 = 0.f;
  float acc4 = 0.f, acc5 = 0.f, acc6 = 0.f, acc7 = 0.f;
  float dsum = 0.f;
  if (half == 0) {  // implicit self loop
    float e = als[n * 4 + h] + ad;
    e = (e > 0.f) ? e : NEG_SLOPE * e;
    float p = __expf(e);
    dsum = p;
    uint4 v = xv[(size_t)n * 32 + hl];
    acc0 = p * asf(v.x << 16); acc1 = p * asf(v.x & 0xffff0000u);
    acc2 = p * asf(v.y << 16); acc3 = p * asf(v.y & 0xffff0000u);
    acc4 = p * asf(v.z << 16); acc5 = p * asf(v.z & 0xffff0000u);
    acc6 = p * asf(v.w << 16); acc7 = p * asf(v.w & 0xffff0000u);
  }
  int beg = offsets[n], end = offsets[n + 1];
  int j = beg;
  for (; j + 8 <= end; j += 8) {
    int s0 = csr_src[j + 0 + half];
    int s1 = csr_src[j + 2 + half];
    int s2 = csr_src[j + 4 + half];
    int s3 = csr_src[j + 6 + half];
    uint4 v0 = xv[(size_t)s0 * 32 + hl];
    uint4 v1 = xv[(size_t)s1 * 32 + hl];
    uint4 v2 = xv[(size_t)s2 * 32 + hl];
    uint4 v3 = xv[(size_t)s3 * 32 + hl];
    float e0 = als[s0 * 4 + h] + ad;
    float e1 = als[s1 * 4 + h] + ad;
    float e2 = als[s2 * 4 + h] + ad;
    float e3 = als[s3 * 4 + h] + ad;
    e0 = (e0 > 0.f) ? e0 : NEG_SLOPE * e0;
    e1 = (e1 > 0.f) ? e1 : NEG_SLOPE * e1;
    e2 = (e2 > 0.f) ? e2 : NEG_SLOPE * e2;
    e3 = (e3 > 0.f) ? e3 : NEG_SLOPE * e3;
    float p0 = __expf(e0);
    float p1 = __expf(e1);
    float p2 = __expf(e2);
    float p3 = __expf(e3);
    dsum += p0 + p1 + p2 + p3;
    acc0 += p0 * asf(v0.x << 16) + p1 * asf(v1.x << 16)
          + p2 * asf(v2.x << 16) + p3 * asf(v3.x << 16);
    acc1 += p0 * asf(v0.x & 0xffff0000u) + p1 * asf(v1.x & 0xffff0000u)
          + p2 * asf(v2.x & 0xffff0000u) + p3 * asf(v3.x & 0xffff0000u);
    acc2 += p0 * asf(v0.y << 16) + p1 * asf(v1.y << 16)
          + p2 * asf(v2.y << 16) + p3 * asf(v3.y << 16);
    acc3 += p0 * asf(v0.y & 0xffff0000u) + p1 * asf(v1.y & 0xffff0000u)
          + p2 * asf(v2.y & 0xffff0000u) + p3 * asf(v3.y & 0xffff0000u);
    acc4 += p0 * asf(v0.z << 16) + p1 * asf(v1.z << 16)
          + p2 * asf(v2.z << 16) + p3 * asf(v3.z << 16);
    acc5 += p0 * asf(v0.z & 0xffff0000u) + p1 * asf(v1.z & 0xffff0000u)
          + p2 * asf(v2.z & 0xffff0000u) + p3 * asf(v3.z & 0xffff0000u);
    acc6 += p0 * asf(v0.w << 16) + p1 * asf(v1.w << 16)
          + p2 * asf(v2.w << 16) + p3 * asf(v3.w << 16);
    acc7 += p0 * asf(v0.w & 0xffff0000u) + p1 * asf(v1.w & 0xffff0000u)
          + p2 * asf(v2.w & 0xffff0000u) + p3 * asf(v3.w & 0xffff0000u);
  }
  for (; j < end; j += 2) {  // remainder: one edge per half
    int jj = j + half;
    if (jj < end) {
      int s = csr_src[jj];
      uint4 v = xv[(size_t)s * 32 + hl];
      float e = als[s * 4 + h] + ad;
      e = (e > 0.f) ? e : NEG_SLOPE * e;
      float p = __expf(e);
      dsum += p;
      acc0 += p * asf(v.x << 16); acc1 += p * asf(v.x & 0xffff0000u);
      acc2 += p * asf(v.y << 16); acc3 += p * asf(v.y & 0xffff0000u);
      acc4 += p * asf(v.z << 16); acc5 += p * asf(v.z & 0xffff0000u);
      acc6 += p * asf(v.w << 16); acc7 += p * asf(v.w & 0xffff0000u);
    }
  }
  // combine halves
  dsum += __shfl_xor(dsum, 32);
  acc0 += __shfl_xor(acc0, 32); acc1 += __shfl_xor(acc1, 32);
  acc2 += __shfl_xor(acc2, 32); acc3 += __shfl_xor(acc3, 32);
  acc4 += __shfl_xor(acc4, 32); acc5 += __shfl_xor(acc5, 32);
  acc6 += __shfl_xor(acc6, 32); acc7 += __shfl_xor(acc7, 32);
  float inv = 1.0f / dsum;
  acc0 *= inv; acc1 *= inv; acc2 *= inv; acc3 *= inv;
  acc4 *= inv; acc5 *= inv; acc6 *= inv; acc7 *= inv;
  // mean over heads: channel c lives in lanes {hl&7, +8, +16, +24}
  acc0 += __shfl_xor(acc0, 8); acc0 += __shfl_xor(acc0, 16);
  acc1 += __shfl_xor(acc1, 8); acc1 += __shfl_xor(acc1, 16);
  acc2 += __shfl_xor(acc2, 8); acc2 += __shfl_xor(acc2, 16);
  acc3 += __shfl_xor(acc3, 8); acc3 += __shfl_xor(acc3, 16);
  acc4 += __shfl_xor(acc4, 8); acc4 += __shfl_xor(acc4, 16);
  acc5 += __shfl_xor(acc5, 8); acc5 += __shfl_xor(acc5, 16);
  acc6 += __shfl_xor(acc6, 8); acc6 += __shfl_xor(acc6, 16);
  acc7 += __shfl_xor(acc7, 8); acc7 += __shfl_xor(acc7, 16);
  if (lane < 8) {
    int f32 = flags[0];
    int cb = 8 * lane;
    float4 o0, o1;
    o0.x = 0.25f * acc0 + loadF(bias, cb + 0, f32);
    o0.y = 0.25f * acc1 + loadF(bias, cb + 1, f32);
    o0.z = 0.25f * acc2 + loadF(bias, cb + 2, f32);
    o0.w = 0.25f * acc3 + loadF(bias, cb + 3, f32);
    o1.x = 0.25f * acc4 + loadF(bias, cb + 4, f32);
    o1.y = 0.25f * acc5 + loadF(bias, cb + 5, f32);
    o1.z = 0.25f * acc6 + loadF(bias, cb + 6, f32);
    o1.w = 0.25f * acc7 + loadF(bias, cb + 7, f32);
    *(float4*)(y + (size_t)n * 64 + cb) = o0;
    *(float4*)(y + (size_t)n * 64 + cb + 4) = o1;
  }
}

// ---------------- BN stats (per-channel sum / sumsq) ----------------
__global__ __launch_bounds__(256) void stats_kernel(const float* __restrict__ y,
                                                    float* __restrict__ gsum,
                                                    float* __restrict__ gsq, int N) {
  __shared__ float ls[256], lq[256];
  int t = threadIdx.x;
  int c = t & 63;
  int r0 = blockIdx.x * 4 + (t >> 6);
  float s = 0.f, q = 0.f;
  for (int r = r0; r < N; r += gridDim.x * 4) {
    float v = y[(size_t)r * 64 + c];
    s += v; q += v * v;
  }
  ls[t] = s; lq[t] = q;
  __syncthreads();
  if (t < 64) {
    s = ls[t] + ls[t + 64] + ls[t + 128] + ls[t + 192];
    q = lq[t] + lq[t + 64] + lq[t + 128] + lq[t + 192];
    atomicAdd(&gsum[c], s);
    atomicAdd(&gsq[c], q);
  }
}

// ---------------- BN apply + ReLU (final output only) ----------------
__global__ __launch_bounds__(256) void bn_kernel(
    const float* __restrict__ y, const float* __restrict__ gsum, const float* __restrict__ gsq,
    const void* __restrict__ gamma, const void* __restrict__ beta,
    const int* __restrict__ flags, float* __restrict__ out_f, int N) {
  int i = blockIdx.x * 256 + threadIdx.x;
  if (i >= N * 16) return;
  int f32 = flags[0];
  int cg = i & 15;
  float4 v = ((const float4*)y)[i];
  float4 s = ((const float4*)gsum)[cg];
  float4 q = ((const float4*)gsq)[cg];
  float inv_n = 1.0f / (float)N;
  float vv[4] = {v.x, v.y, v.z, v.w};
  float ss[4] = {s.x, s.y, s.z, s.w};
  float qq[4] = {q.x, q.y, q.z, q.w};
  float o[4];
  #pragma unroll
  for (int k = 0; k < 4; k++) {
    float g = loadF(gamma, 4 * cg + k, f32);
    float b = loadF(beta, 4 * cg + k, f32);
    float mu = ss[k] * inv_n;
    float var = fmaxf(qq[k] * inv_n - mu * mu, 0.f);
    float r = g * (vv[k] - mu) * rsqrtf(var + BN_EPS) + b;
    o[k] = r > 0.f ? r : 0.f;
  }
  float4 ov; ov.x = o[0]; ov.y = o[1]; ov.z = o[2]; ov.w = o[3];
  ((float4*)out_f)[i] = ov;
}

// ---------------- launch ----------------
extern "C" void kernel_launch(void* const* d_in, const int* in_sizes, int n_in,
                              void* d_out, int out_size, void* d_ws, size_t ws_size,
                              hipStream_t stream) {
  const void* x    = d_in[0];
  const void* ei   = d_in[1];
  const void* W0    = d_in[3];
  const void* asrc0 = d_in[4];
  const void* adst0 = d_in[5];
  const void* b0    = d_in[6];
  const void* g0    = d_in[7];
  const void* be0   = d_in[8];
  const void* W1    = d_in[9];
  const void* asrc1 = d_in[10];
  const void* adst1 = d_in[11];
  const void* b1    = d_in[12];
  const void* g1    = d_in[13];
  const void* be1   = d_in[14];

  int N = in_sizes[0] / 64;
  int E = in_sizes[1] / 2;
  int NG = (N + 255) / 256;    // gemm blocks (256 rows each)
  int NA = (N + 3) / 4;        // agg blocks: one node per wave

  char* p = (char*)d_ws;
  auto alloc = [&](size_t bytes) -> char* {
    char* r = p;
    p += (bytes + 255) & ~(size_t)255;
    return r;
  };
  int* flags    = (int*)alloc(256);
  int* deg      = (int*)alloc((size_t)N * 4);
  int* cursor   = (int*)alloc((size_t)N * 4);
  int* offsets  = (int*)alloc((size_t)(N + 1) * 4);
  int* csr_src  = (int*)alloc((size_t)E * 4);
  unsigned short* WTx0 = (unsigned short*)alloc(272 * 64 * 2);
  unsigned short* WTx1 = (unsigned short*)alloc(272 * 64 * 2);
  unsigned short* xh = (unsigned short*)alloc((size_t)N * 256 * 2);
  float* als    = (float*)alloc((size_t)N * 4 * 4);
  float* ald    = (float*)alloc((size_t)N * 4 * 4);
  float* y      = (float*)alloc((size_t)N * 64 * 4);
  float* gsum0  = (float*)alloc(256);
  float* gsq0   = (float*)alloc(256);
  float* gsum1  = (float*)alloc(256);
  float* gsq1   = (float*)alloc(256);

  hipMemsetAsync(deg, 0, (size_t)N * 4, stream);
  hipMemsetAsync(gsum0, 0, 1024, stream);  // gsum0..gsq1 contiguous

  wtrans_kernel<<<2, 256, 0, stream>>>((const unsigned short*)x, (const int*)ei,
                                       W0, asrc0, adst0, W1, asrc1, adst1, flags, WTx0, WTx1);

  hist_kernel<<<(E + 255) / 256, 256, 0, stream>>>(ei, E, N, flags, deg);
  scan_kernel<<<1, 1024, 0, stream>>>(deg, offsets, cursor, N);
  scatter_kernel<<<(E + 255) / 256, 256, 0, stream>>>(ei, E, N, flags, cursor, csr_src);

  float* out_x = (float*)d_out;                    // output 0: final, fp32
  float* out_saved = out_x + (size_t)N * 64;       // output 1: layer-2 pre-BN, fp32

  // ---- layer 0 ----
  gemm_mfma<<<NG, 256, 0, stream>>>(x, WTx0, flags, 0, (const float*)nullptr,
                                    (const float*)nullptr, nullptr, nullptr,
                                    xh, als, ald, N);
  agg_kernel<<<NA, 256, 0, stream>>>(xh, als, ald, offsets, csr_src, b0, flags, y, N);
  stats_kernel<<<250, 256, 0, stream>>>(y, gsum0, gsq0, N);
  // ---- layer 1 (BN of layer 0 fused into gemm A-load) ----
  gemm_mfma<<<NG, 256, 0, stream>>>(y, WTx1, flags, 1, gsum0, gsq0, g0, be0,
                                    xh, als, ald, N);
  agg_kernel<<<NA, 256, 0, stream>>>(xh, als, ald, offsets, csr_src, b1, flags, out_saved, N);
  stats_kernel<<<250, 256, 0, stream>>>(out_saved, gsum1, gsq1, N);
  bn_kernel<<<(N * 16 + 255) / 256, 256, 0, stream>>>(out_saved, gsum1, gsq1, g1, be1,
                                                      flags, out_x, N);
}

// Round 13
// 434.200 us; speedup vs baseline: 1.2658x; 1.2658x over previous
//
#include <hip/hip_runtime.h>
#include <stdint.h>

#define NEG_SLOPE 0.2f
#define BN_EPS 1e-5f

typedef __attribute__((ext_vector_type(8))) short bf16x8;
typedef __attribute__((ext_vector_type(4))) float f32x4;

// ---------------- bf16 helpers ----------------
__device__ __forceinline__ float bf2f(unsigned short u) {
  union { unsigned int i; float f; } v; v.i = ((unsigned int)u) << 16; return v.f;
}
__device__ __forceinline__ float asf(unsigned int u) {
  union { unsigned int i; float f; } v; v.i = u; return v.f;
}
__device__ __forceinline__ unsigned short f2bf(float f) {
  union { float f; unsigned int i; } v; v.f = f;
  unsigned int i = v.i;
  return (unsigned short)((i + 0x7fffu + ((i >> 16) & 1u)) >> 16);  // RNE
}
__device__ __forceinline__ float loadF(const void* p, long long i, int f32) {
  return f32 ? ((const float*)p)[i] : bf2f(((const unsigned short*)p)[i]);
}
__device__ __forceinline__ int edge_at(const void* ei, long long idx, int is64) {
  return is64 ? (int)((const long long*)ei)[idx] : ((const int*)ei)[idx];
}

// ---------------- W preprocessing + inline dtype detection ----------------
// Each block detects dtype locally (LDS); block 0 publishes flags for later kernels.
// WTx [272 rows][64 k] bf16: rows 0..255 = W^T; 256..259 = Ws[h]; 260..263 = Wd[h]; 264..271 = 0.
__global__ __launch_bounds__(256) void wtrans_kernel(
    const unsigned short* __restrict__ x, const int* __restrict__ ei32,
    const void* __restrict__ W0, const void* __restrict__ as0, const void* __restrict__ ad0,
    const void* __restrict__ W1, const void* __restrict__ as1, const void* __restrict__ ad1,
    int* __restrict__ flags,
    unsigned short* __restrict__ WTx0, unsigned short* __restrict__ WTx1) {
  __shared__ int wild, oddnz;
  __shared__ unsigned short Wl[64 * 258];
  int t = threadIdx.x;
  if (t == 0) { wild = 0; oddnz = 0; }
  __syncthreads();
  {
    int lw = 0, lo = 0;
    for (int i = t; i < 4096; i += 256) {
      unsigned short u = x[i];
      int ex = (u >> 7) & 0xFF;
      if (ex >= 0x86) lw++;               // impossible exponent for N(0,1) bf16
      if (ei32[2 * i + 1] != 0) lo++;     // int64 high words all zero
    }
    if (lw) atomicAdd(&wild, lw);
    if (lo) atomicAdd(&oddnz, lo);
  }
  __syncthreads();
  int f32 = (wild > 64) ? 1 : 0;
  if (blockIdx.x == 0 && t == 0) { flags[0] = f32; flags[1] = (oddnz == 0) ? 1 : 0; }

  const void* W = blockIdx.x ? W1 : W0;
  const void* asrc = blockIdx.x ? as1 : as0;
  const void* adst = blockIdx.x ? ad1 : ad0;
  unsigned short* WTx = blockIdx.x ? WTx1 : WTx0;
  for (int i = t; i < 64 * 256; i += 256) {
    int k = i >> 8, c = i & 255;
    Wl[k * 258 + c] = f32 ? f2bf(((const float*)W)[i]) : ((const unsigned short*)W)[i];
  }
  __syncthreads();
  {
    int c = t;
    #pragma unroll
    for (int k8 = 0; k8 < 64; k8 += 8) {
      unsigned int p0 = (unsigned int)Wl[(k8 + 0) * 258 + c] | ((unsigned int)Wl[(k8 + 1) * 258 + c] << 16);
      unsigned int p1 = (unsigned int)Wl[(k8 + 2) * 258 + c] | ((unsigned int)Wl[(k8 + 3) * 258 + c] << 16);
      unsigned int p2 = (unsigned int)Wl[(k8 + 4) * 258 + c] | ((unsigned int)Wl[(k8 + 5) * 258 + c] << 16);
      unsigned int p3 = (unsigned int)Wl[(k8 + 6) * 258 + c] | ((unsigned int)Wl[(k8 + 7) * 258 + c] << 16);
      uint4 pk; pk.x = p0; pk.y = p1; pk.z = p2; pk.w = p3;
      *(uint4*)&WTx[c * 64 + k8] = pk;
    }
  }
  for (int idx = t; idx < 512; idx += 256) {
    int r = idx >> 6;
    int k = idx & 63;
    int h = r & 3;
    const void* av = (r >> 2) ? adst : asrc;
    float acc = 0.f;
    #pragma unroll 8
    for (int c = 0; c < 64; c++)
      acc += bf2f(Wl[k * 258 + h * 64 + c]) * loadF(av, h * 64 + c, f32);
    WTx[(256 + r) * 64 + k] = f2bf(acc);
  }
  for (int idx = t; idx < 512; idx += 256) WTx[264 * 64 + idx] = 0;
}

// ---------------- CSR build ----------------
__global__ __launch_bounds__(256) void hist_kernel(const void* __restrict__ ei, int E, int N,
                                                   const int* __restrict__ flags,
                                                   int* __restrict__ deg) {
  int e = blockIdx.x * 256 + threadIdx.x;
  if (e >= E) return;
  int is64 = flags[1];
  int d = edge_at(ei, (long long)E + e, is64);
  d = (d < 0 || d >= N) ? 0 : d;
  atomicAdd(&deg[d], 1);
}

// hierarchical scan: per-block sums -> single-wave scan of block sums -> per-block final
__global__ __launch_bounds__(256) void partial_kernel(const int* __restrict__ deg,
                                                      int* __restrict__ blocksum, int N) {
  int t = threadIdx.x;
  int idx = blockIdx.x * 256 + t;
  int v = (idx < N) ? deg[idx] : 0;
  #pragma unroll
  for (int o = 1; o < 64; o <<= 1) v += __shfl_xor(v, o);
  __shared__ int ws[4];
  if ((t & 63) == 0) ws[t >> 6] = v;
  __syncthreads();
  if (t == 0) blocksum[blockIdx.x] = ws[0] + ws[1] + ws[2] + ws[3];
}

__global__ void scan_base_kernel(const int* __restrict__ blocksum,
                                 int* __restrict__ blockbase, int B) {
  int lane = threadIdx.x;
  int base = 0;
  if (lane == 0) blockbase[0] = 0;
  for (int start = 0; start < B; start += 64) {
    int idx = start + lane;
    int v = (idx < B) ? blocksum[idx] : 0;
    int sc = v;
    #pragma unroll
    for (int o = 1; o < 64; o <<= 1) {
      int u = __shfl_up(sc, o);
      if (lane >= o) sc += u;
    }
    if (idx < B) blockbase[idx + 1] = base + sc;
    base = __shfl(base + sc, 63);
  }
}

// final: offsets[idx+1] = inclusive prefix; cursor[idx] = exclusive prefix (scatter slots)
__global__ __launch_bounds__(256) void scan_final_kernel(const int* __restrict__ deg,
                                                         const int* __restrict__ blockbase,
                                                         int* __restrict__ offsets,
                                                         int* __restrict__ cursor, int N) {
  int t = threadIdx.x;
  int lane = t & 63;
  int wid = t >> 6;
  int idx = blockIdx.x * 256 + t;
  int v = (idx < N) ? deg[idx] : 0;
  int sc = v;
  #pragma unroll
  for (int o = 1; o < 64; o <<= 1) {
    int u = __shfl_up(sc, o);
    if (lane >= o) sc += u;
  }
  __shared__ int ws[4];
  if (lane == 63) ws[wid] = sc;
  __syncthreads();
  int add = 0;
  #pragma unroll
  for (int w = 0; w < 4; w++) if (w < wid) add += ws[w];
  int incl = blockbase[blockIdx.x] + add + sc;
  if (idx < N) {
    offsets[idx + 1] = incl;
    cursor[idx] = incl - v;          // exclusive prefix = first slot for node idx
  }
  if (idx == 0) offsets[0] = 0;
}

__global__ __launch_bounds__(256) void scatter_kernel(
    const void* __restrict__ ei, int E, int N, const int* __restrict__ flags,
    int* __restrict__ cursor, int* __restrict__ csr_src) {
  int e = blockIdx.x * 256 + threadIdx.x;
  if (e >= E) return;
  int is64 = flags[1];
  int s = edge_at(ei, e, is64);
  int d = edge_at(ei, (long long)E + e, is64);
  s = (s < 0 || s >= N) ? 0 : s;
  d = (d < 0 || d >= N) ? 0 : d;
  int pos = atomicAdd(&cursor[d], 1);
  csr_src[pos] = s;
}

// ---------------- MFMA GEMM: xh = x @ W (bf16) + als/ald tile; optional fused BN ----------------
// 128 rows per block (2 row-tiles share one WTx staging). mode 1: BN+ReLU fused A-load.
__global__ __launch_bounds__(256, 3) void gemm_mfma(
    const void* __restrict__ x, const unsigned short* __restrict__ WTx,
    const int* __restrict__ flags, int mode,
    const float* __restrict__ gsum, const float* __restrict__ gsq,
    const void* __restrict__ gamma, const void* __restrict__ beta,
    unsigned short* __restrict__ xh, float* __restrict__ als, float* __restrict__ ald,
    int N) {
  __shared__ unsigned short WTs[272 * 68];    // 36 KB staged weights
  __shared__ unsigned short RP[4][16 * 68];   // per-wave repack chunk (8.5 KB)
  __shared__ float bnsc[64], bnsh[64];
  int f32 = flags[0];
  int t = threadIdx.x;
  for (int i = t; i < 272 * 8; i += 256) {
    int c = i >> 3, g = i & 7;
    uint4 v = ((const uint4*)WTx)[i];
    *(uint4*)&WTs[c * 68 + g * 8] = v;
  }
  if (mode == 1 && t < 64) {
    float mu = gsum[t] / (float)N;
    float var = fmaxf(gsq[t] / (float)N - mu * mu, 0.f);
    float sc = loadF(gamma, t, f32) * rsqrtf(var + BN_EPS);
    bnsc[t] = sc;
    bnsh[t] = loadF(beta, t, f32) - mu * sc;
  }
  __syncthreads();

  int wave = t >> 6, lane = t & 63;
  int q = lane >> 4, r16 = lane & 15;
  unsigned short* rp = RP[wave];

  #pragma unroll
  for (int rb = 0; rb < 2; rb++) {
    int m0 = blockIdx.x * 128 + rb * 64 + wave * 16;
    if (m0 >= N) break;
    int row = m0 + r16;
    int rowc = row < N ? row : N - 1;

    bf16x8 a0, a1;
    if (mode == 1) {
      const float* xp = (const float*)x + (size_t)rowc * 64 + q * 8;
      float va[8], vb[8];
      *(float4*)&va[0] = ((const float4*)xp)[0];
      *(float4*)&va[4] = ((const float4*)xp)[1];
      *(float4*)&vb[0] = ((const float4*)(xp + 32))[0];
      *(float4*)&vb[4] = ((const float4*)(xp + 32))[1];
      int k0 = q * 8;
      #pragma unroll
      for (int jj = 0; jj < 8; jj++) {
        float v = fmaxf(va[jj] * bnsc[k0 + jj] + bnsh[k0 + jj], 0.f);
        float w = fmaxf(vb[jj] * bnsc[k0 + 32 + jj] + bnsh[k0 + 32 + jj], 0.f);
        a0[jj] = (short)f2bf(v);
        a1[jj] = (short)f2bf(w);
      }
    } else if (f32) {
      const float* xp = (const float*)x + (size_t)rowc * 64 + q * 8;
      float va[8], vb[8];
      *(float4*)&va[0] = ((const float4*)xp)[0];
      *(float4*)&va[4] = ((const float4*)xp)[1];
      *(float4*)&vb[0] = ((const float4*)(xp + 32))[0];
      *(float4*)&vb[4] = ((const float4*)(xp + 32))[1];
      #pragma unroll
      for (int jj = 0; jj < 8; jj++) {
        a0[jj] = (short)f2bf(va[jj]);
        a1[jj] = (short)f2bf(vb[jj]);
      }
    } else {
      const unsigned short* xp = (const unsigned short*)x + (size_t)rowc * 64 + q * 8;
      a0 = *(const bf16x8*)xp;
      a1 = *(const bf16x8*)(xp + 32);
    }

    f32x4 acc[17];
    #pragma unroll
    for (int tt = 0; tt < 17; tt++) acc[tt] = (f32x4){0.f, 0.f, 0.f, 0.f};
    #pragma unroll
    for (int tt = 0; tt < 17; tt++) {
      int c = tt * 16 + r16;
      bf16x8 b0 = *(const bf16x8*)&WTs[c * 68 + q * 8];
      bf16x8 b1 = *(const bf16x8*)&WTs[c * 68 + 32 + q * 8];
      acc[tt] = __builtin_amdgcn_mfma_f32_16x16x32_bf16(a0, b0, acc[tt], 0, 0, 0);
      acc[tt] = __builtin_amdgcn_mfma_f32_16x16x32_bf16(a1, b1, acc[tt], 0, 0, 0);
    }

    // epilogue 1: als/ald from tile 16
    {
      int obase = m0 + q * 4;
      #pragma unroll
      for (int rr = 0; rr < 4; rr++) {
        int orow = obase + rr;
        if (orow < N) {
          if (r16 < 4) als[orow * 4 + r16] = acc[16][rr];
          else if (r16 < 8) ald[orow * 4 + (r16 - 4)] = acc[16][rr];
        }
      }
    }
    // epilogue 2: 4 chunked passes, per-wave LDS repack (wave-internal, no barrier)
    #pragma unroll
    for (int g4 = 0; g4 < 4; g4++) {
      #pragma unroll
      for (int tt2 = 0; tt2 < 4; tt2++) {
        int tile = g4 * 4 + tt2;
        #pragma unroll
        for (int rr = 0; rr < 4; rr++)
          rp[(q * 4 + rr) * 68 + tt2 * 16 + r16] = f2bf(acc[tile][rr]);
      }
      #pragma unroll
      for (int i = 0; i < 2; i++) {
        int g = i * 64 + lane;
        int r = g >> 3;
        int grp = g & 7;
        uint4 v = *(const uint4*)&rp[r * 68 + grp * 8];
        int orow = m0 + r;
        if (orow < N) ((uint4*)xh)[(size_t)orow * 32 + g4 * 8 + grp] = v;
      }
    }
  }
}

// ---------------- per-dst-node softmax aggregation ----------------
// One node per wave (one-shot frame). Half-wave edge pairing; 8 edges per unrolled iter.
__global__ __launch_bounds__(256) void agg_kernel(
    const unsigned short* __restrict__ xh,
    const float* __restrict__ als, const float* __restrict__ ald,
    const int* __restrict__ offsets, const int* __restrict__ csr_src,
    const void* __restrict__ bias, const int* __restrict__ flags,
    float* __restrict__ y, int N) {
  int lane = threadIdx.x & 63;
  int wid = threadIdx.x >> 6;
  int n = blockIdx.x * 4 + wid;
  if (n >= N) return;
  int half = lane >> 5;     // 0: even slots + self, 1: odd slots
  int hl = lane & 31;       // channels 8*hl .. 8*hl+7
  int h = hl >> 3;          // head
  const uint4* xv = (const uint4*)xh;
  float ad = ald[n * 4 + h];
  float acc0 = 0.f, acc1 = 0.f, acc2 = 0.f, acc3 = 0.f;
  float acc4 = 0.f, acc5 = 0.f, acc6 = 0.f, acc7 = 0.f;
  float dsum = 0.f;
  if (half == 0) {  // implicit self loop
    float e = als[n * 4 + h] + ad;
    e = (e > 0.f) ? e : NEG_SLOPE * e;
    float p = __expf(e);
    dsum = p;
    uint4 v = xv[(size_t)n * 32 + hl];
    acc0 = p * asf(v.x << 16); acc1 = p * asf(v.x & 0xffff0000u);
    acc2 = p * asf(v.y << 16); acc3 = p * asf(v.y & 0xffff0000u);
    acc4 = p * asf(v.z << 16); acc5 = p * asf(v.z & 0xffff0000u);
    acc6 = p * asf(v.w << 16); acc7 = p * asf(v.w & 0xffff0000u);
  }
  int beg = offsets[n], end = offsets[n + 1];
  int j = beg;
  for (; j + 8 <= end; j += 8) {
    int s0 = csr_src[j + 0 + half];
    int s1 = csr_src[j + 2 + half];
    int s2 = csr_src[j + 4 + half];
    int s3 = csr_src[j + 6 + half];
    uint4 v0 = xv[(size_t)s0 * 32 + hl];
    uint4 v1 = xv[(size_t)s1 * 32 + hl];
    uint4 v2 = xv[(size_t)s2 * 32 + hl];
    uint4 v3 = xv[(size_t)s3 * 32 + hl];
    float e0 = als[s0 * 4 + h] + ad;
    float e1 = als[s1 * 4 + h] + ad;
    float e2 = als[s2 * 4 + h] + ad;
    float e3 = als[s3 * 4 + h] + ad;
    e0 = (e0 > 0.f) ? e0 : NEG_SLOPE * e0;
    e1 = (e1 > 0.f) ? e1 : NEG_SLOPE * e1;
    e2 = (e2 > 0.f) ? e2 : NEG_SLOPE * e2;
    e3 = (e3 > 0.f) ? e3 : NEG_SLOPE * e3;
    float p0 = __expf(e0);
    float p1 = __expf(e1);
    float p2 = __expf(e2);
    float p3 = __expf(e3);
    dsum += p0 + p1 + p2 + p3;
    acc0 += p0 * asf(v0.x << 16) + p1 * asf(v1.x << 16)
          + p2 * asf(v2.x << 16) + p3 * asf(v3.x << 16);
    acc1 += p0 * asf(v0.x & 0xffff0000u) + p1 * asf(v1.x & 0xffff0000u)
          + p2 * asf(v2.x & 0xffff0000u) + p3 * asf(v3.x & 0xffff0000u);
    acc2 += p0 * asf(v0.y << 16) + p1 * asf(v1.y << 16)
          + p2 * asf(v2.y << 16) + p3 * asf(v3.y << 16);
    acc3 += p0 * asf(v0.y & 0xffff0000u) + p1 * asf(v1.y & 0xffff0000u)
          + p2 * asf(v2.y & 0xffff0000u) + p3 * asf(v3.y & 0xffff0000u);
    acc4 += p0 * asf(v0.z << 16) + p1 * asf(v1.z << 16)
          + p2 * asf(v2.z << 16) + p3 * asf(v3.z << 16);
    acc5 += p0 * asf(v0.z & 0xffff0000u) + p1 * asf(v1.z & 0xffff0000u)
          + p2 * asf(v2.z & 0xffff0000u) + p3 * asf(v3.z & 0xffff0000u);
    acc6 += p0 * asf(v0.w << 16) + p1 * asf(v1.w << 16)
          + p2 * asf(v2.w << 16) + p3 * asf(v3.w << 16);
    acc7 += p0 * asf(v0.w & 0xffff0000u) + p1 * asf(v1.w & 0xffff0000u)
          + p2 * asf(v2.w & 0xffff0000u) + p3 * asf(v3.w & 0xffff0000u);
  }
  for (; j < end; j += 2) {  // remainder: one edge per half
    int jj = j + half;
    if (jj < end) {
      int s = csr_src[jj];
      uint4 v = xv[(size_t)s * 32 + hl];
      float e = als[s * 4 + h] + ad;
      e = (e > 0.f) ? e : NEG_SLOPE * e;
      float p = __expf(e);
      dsum += p;
      acc0 += p * asf(v.x << 16); acc1 += p * asf(v.x & 0xffff0000u);
      acc2 += p * asf(v.y << 16); acc3 += p * asf(v.y & 0xffff0000u);
      acc4 += p * asf(v.z << 16); acc5 += p * asf(v.z & 0xffff0000u);
      acc6 += p * asf(v.w << 16); acc7 += p * asf(v.w & 0xffff0000u);
    }
  }
  // combine halves
  dsum += __shfl_xor(dsum, 32);
  acc0 += __shfl_xor(acc0, 32); acc1 += __shfl_xor(acc1, 32);
  acc2 += __shfl_xor(acc2, 32); acc3 += __shfl_xor(acc3, 32);
  acc4 += __shfl_xor(acc4, 32); acc5 += __shfl_xor(acc5, 32);
  acc6 += __shfl_xor(acc6, 32); acc7 += __shfl_xor(acc7, 32);
  float inv = 1.0f / dsum;
  acc0 *= inv; acc1 *= inv; acc2 *= inv; acc3 *= inv;
  acc4 *= inv; acc5 *= inv; acc6 *= inv; acc7 *= inv;
  // mean over heads: channel c lives in lanes {hl&7, +8, +16, +24}
  acc0 += __shfl_xor(acc0, 8); acc0 += __shfl_xor(acc0, 16);
  acc1 += __shfl_xor(acc1, 8); acc1 += __shfl_xor(acc1, 16);
  acc2 += __shfl_xor(acc2, 8); acc2 += __shfl_xor(acc2, 16);
  acc3 += __shfl_xor(acc3, 8); acc3 += __shfl_xor(acc3, 16);
  acc4 += __shfl_xor(acc4, 8); acc4 += __shfl_xor(acc4, 16);
  acc5 += __shfl_xor(acc5, 8); acc5 += __shfl_xor(acc5, 16);
  acc6 += __shfl_xor(acc6, 8); acc6 += __shfl_xor(acc6, 16);
  acc7 += __shfl_xor(acc7, 8); acc7 += __shfl_xor(acc7, 16);
  if (lane < 8) {
    int f32 = flags[0];
    int cb = 8 * lane;
    float4 o0, o1;
    o0.x = 0.25f * acc0 + loadF(bias, cb + 0, f32);
    o0.y = 0.25f * acc1 + loadF(bias, cb + 1, f32);
    o0.z = 0.25f * acc2 + loadF(bias, cb + 2, f32);
    o0.w = 0.25f * acc3 + loadF(bias, cb + 3, f32);
    o1.x = 0.25f * acc4 + loadF(bias, cb + 4, f32);
    o1.y = 0.25f * acc5 + loadF(bias, cb + 5, f32);
    o1.z = 0.25f * acc6 + loadF(bias, cb + 6, f32);
    o1.w = 0.25f * acc7 + loadF(bias, cb + 7, f32);
    *(float4*)(y + (size_t)n * 64 + cb) = o0;
    *(float4*)(y + (size_t)n * 64 + cb + 4) = o1;
  }
}

// ---------------- BN stats (per-channel sum / sumsq) ----------------
__global__ __launch_bounds__(256) void stats_kernel(const float* __restrict__ y,
                                                    float* __restrict__ gsum,
                                                    float* __restrict__ gsq, int N) {
  __shared__ float ls[256], lq[256];
  int t = threadIdx.x;
  int c = t & 63;
  int r0 = blockIdx.x * 4 + (t >> 6);
  float s = 0.f, q = 0.f;
  for (int r = r0; r < N; r += gridDim.x * 4) {
    float v = y[(size_t)r * 64 + c];
    s += v; q += v * v;
  }
  ls[t] = s; lq[t] = q;
  __syncthreads();
  if (t < 64) {
    s = ls[t] + ls[t + 64] + ls[t + 128] + ls[t + 192];
    q = lq[t] + lq[t + 64] + lq[t + 128] + lq[t + 192];
    atomicAdd(&gsum[c], s);
    atomicAdd(&gsq[c], q);
  }
}

// ---------------- BN apply + ReLU (final output only) ----------------
__global__ __launch_bounds__(256) void bn_kernel(
    const float* __restrict__ y, const float* __restrict__ gsum, const float* __restrict__ gsq,
    const void* __restrict__ gamma, const void* __restrict__ beta,
    const int* __restrict__ flags, float* __restrict__ out_f, int N) {
  int i = blockIdx.x * 256 + threadIdx.x;
  if (i >= N * 16) return;
  int f32 = flags[0];
  int cg = i & 15;
  float4 v = ((const float4*)y)[i];
  float4 s = ((const float4*)gsum)[cg];
  float4 q = ((const float4*)gsq)[cg];
  float inv_n = 1.0f / (float)N;
  float vv[4] = {v.x, v.y, v.z, v.w};
  float ss[4] = {s.x, s.y, s.z, s.w};
  float qq[4] = {q.x, q.y, q.z, q.w};
  float o[4];
  #pragma unroll
  for (int k = 0; k < 4; k++) {
    float g = loadF(gamma, 4 * cg + k, f32);
    float b = loadF(beta, 4 * cg + k, f32);
    float mu = ss[k] * inv_n;
    float var = fmaxf(qq[k] * inv_n - mu * mu, 0.f);
    float r = g * (vv[k] - mu) * rsqrtf(var + BN_EPS) + b;
    o[k] = r > 0.f ? r : 0.f;
  }
  float4 ov; ov.x = o[0]; ov.y = o[1]; ov.z = o[2]; ov.w = o[3];
  ((float4*)out_f)[i] = ov;
}

// ---------------- launch ----------------
extern "C" void kernel_launch(void* const* d_in, const int* in_sizes, int n_in,
                              void* d_out, int out_size, void* d_ws, size_t ws_size,
                              hipStream_t stream) {
  const void* x    = d_in[0];
  const void* ei   = d_in[1];
  const void* W0    = d_in[3];
  const void* asrc0 = d_in[4];
  const void* adst0 = d_in[5];
  const void* b0    = d_in[6];
  const void* g0    = d_in[7];
  const void* be0   = d_in[8];
  const void* W1    = d_in[9];
  const void* asrc1 = d_in[10];
  const void* adst1 = d_in[11];
  const void* b1    = d_in[12];
  const void* g1    = d_in[13];
  const void* be1   = d_in[14];

  int N = in_sizes[0] / 64;
  int E = in_sizes[1] / 2;
  int NB = (N + 255) / 256;    // scan blocks
  int NG = (N + 127) / 128;    // gemm blocks (128 rows each)
  int NA = (N + 3) / 4;        // agg blocks: one node per wave

  char* p = (char*)d_ws;
  auto alloc = [&](size_t bytes) -> char* {
    char* r = p;
    p += (bytes + 255) & ~(size_t)255;
    return r;
  };
  int* flags    = (int*)alloc(256);
  int* deg      = (int*)alloc((size_t)N * 4);
  int* cursor   = (int*)alloc((size_t)N * 4);
  int* offsets  = (int*)alloc((size_t)(N + 1) * 4);
  int* blocksum = (int*)alloc((size_t)NB * 4);
  int* blockbase= (int*)alloc((size_t)(NB + 1) * 4);
  int* csr_src  = (int*)alloc((size_t)E * 4);
  unsigned short* WTx0 = (unsigned short*)alloc(272 * 64 * 2);
  unsigned short* WTx1 = (unsigned short*)alloc(272 * 64 * 2);
  unsigned short* xh = (unsigned short*)alloc((size_t)N * 256 * 2);
  float* als    = (float*)alloc((size_t)N * 4 * 4);
  float* ald    = (float*)alloc((size_t)N * 4 * 4);
  float* y      = (float*)alloc((size_t)N * 64 * 4);
  float* gsum0  = (float*)alloc(256);
  float* gsq0   = (float*)alloc(256);
  float* gsum1  = (float*)alloc(256);
  float* gsq1   = (float*)alloc(256);

  hipMemsetAsync(deg, 0, (size_t)N * 4, stream);
  hipMemsetAsync(gsum0, 0, 1024, stream);  // gsum0..gsq1 contiguous

  wtrans_kernel<<<2, 256, 0, stream>>>((const unsigned short*)x, (const int*)ei,
                                       W0, asrc0, adst0, W1, asrc1, adst1, flags, WTx0, WTx1);

  hist_kernel<<<(E + 255) / 256, 256, 0, stream>>>(ei, E, N, flags, deg);
  partial_kernel<<<NB, 256, 0, stream>>>(deg, blocksum, N);
  scan_base_kernel<<<1, 64, 0, stream>>>(blocksum, blockbase, NB);
  scan_final_kernel<<<NB, 256, 0, stream>>>(deg, blockbase, offsets, cursor, N);
  scatter_kernel<<<(E + 255) / 256, 256, 0, stream>>>(ei, E, N, flags, cursor, csr_src);

  float* out_x = (float*)d_out;                    // output 0: final, fp32
  float* out_saved = out_x + (size_t)N * 64;       // output 1: layer-2 pre-BN, fp32

  // ---- layer 0 ----
  gemm_mfma<<<NG, 256, 0, stream>>>(x, WTx0, flags, 0, (const float*)nullptr,
                                    (const float*)nullptr, nullptr, nullptr,
                                    xh, als, ald, N);
  agg_kernel<<<NA, 256, 0, stream>>>(xh, als, ald, offsets, csr_src, b0, flags, y, N);
  stats_kernel<<<782, 256, 0, stream>>>(y, gsum0, gsq0, N);
  // ---- layer 1 (BN of layer 0 fused into gemm A-load) ----
  gemm_mfma<<<NG, 256, 0, stream>>>(y, WTx1, flags, 1, gsum0, gsq0, g0, be0,
                                    xh, als, ald, N);
  agg_kernel<<<NA, 256, 0, stream>>>(xh, als, ald, offsets, csr_src, b1, flags, out_saved, N);
  stats_kernel<<<782, 256, 0, stream>>>(out_saved, gsum1, gsq1, N);
  bn_kernel<<<(N * 16 + 255) / 256, 256, 0, stream>>>(out_saved, gsum1, gsq1, g1, be1,
                                                      flags, out_x, N);
}

// Round 14
// 411.258 us; speedup vs baseline: 1.3364x; 1.0558x over previous
//
#include <hip/hip_runtime.h>
#include <stdint.h>

#define NEG_SLOPE 0.2f
#define BN_EPS 1e-5f

typedef __attribute__((ext_vector_type(8))) short bf16x8;
typedef __attribute__((ext_vector_type(4))) float f32x4;

// ---------------- bf16 helpers ----------------
__device__ __forceinline__ float bf2f(unsigned short u) {
  union { unsigned int i; float f; } v; v.i = ((unsigned int)u) << 16; return v.f;
}
__device__ __forceinline__ float asf(unsigned int u) {
  union { unsigned int i; float f; } v; v.i = u; return v.f;
}
__device__ __forceinline__ unsigned short f2bf(float f) {
  union { float f; unsigned int i; } v; v.f = f;
  unsigned int i = v.i;
  return (unsigned short)((i + 0x7fffu + ((i >> 16) & 1u)) >> 16);  // RNE
}
__device__ __forceinline__ float loadF(const void* p, long long i, int f32) {
  return f32 ? ((const float*)p)[i] : bf2f(((const unsigned short*)p)[i]);
}
__device__ __forceinline__ int edge_at(const void* ei, long long idx, int is64) {
  return is64 ? (int)((const long long*)ei)[idx] : ((const int*)ei)[idx];
}

// ---------------- W preprocessing + inline dtype detection ----------------
// Each block detects dtype locally (LDS); block 0 publishes flags for later kernels.
// WTx [272 rows][64 k] bf16: rows 0..255 = W^T; 256..259 = Ws[h]; 260..263 = Wd[h]; 264..271 = 0.
__global__ __launch_bounds__(256) void wtrans_kernel(
    const unsigned short* __restrict__ x, const int* __restrict__ ei32,
    const void* __restrict__ W0, const void* __restrict__ as0, const void* __restrict__ ad0,
    const void* __restrict__ W1, const void* __restrict__ as1, const void* __restrict__ ad1,
    int* __restrict__ flags,
    unsigned short* __restrict__ WTx0, unsigned short* __restrict__ WTx1) {
  __shared__ int wild, oddnz;
  __shared__ unsigned short Wl[64 * 258];
  int t = threadIdx.x;
  if (t == 0) { wild = 0; oddnz = 0; }
  __syncthreads();
  {
    int lw = 0, lo = 0;
    for (int i = t; i < 4096; i += 256) {
      unsigned short u = x[i];
      int ex = (u >> 7) & 0xFF;
      if (ex >= 0x86) lw++;               // impossible exponent for N(0,1) bf16
      if (ei32[2 * i + 1] != 0) lo++;     // int64 high words all zero
    }
    if (lw) atomicAdd(&wild, lw);
    if (lo) atomicAdd(&oddnz, lo);
  }
  __syncthreads();
  int f32 = (wild > 64) ? 1 : 0;
  if (blockIdx.x == 0 && t == 0) { flags[0] = f32; flags[1] = (oddnz == 0) ? 1 : 0; }

  const void* W = blockIdx.x ? W1 : W0;
  const void* asrc = blockIdx.x ? as1 : as0;
  const void* adst = blockIdx.x ? ad1 : ad0;
  unsigned short* WTx = blockIdx.x ? WTx1 : WTx0;
  // vectorized W load -> Wl (bf16, pad 258)
  if (f32) {
    for (int i = t; i < 4096; i += 256) {       // 4096 float4 groups
      float4 w = ((const float4*)W)[i];
      int base = i * 4;
      int k = base >> 8, c = base & 255;
      unsigned short* d = &Wl[k * 258 + c];
      d[0] = f2bf(w.x); d[1] = f2bf(w.y); d[2] = f2bf(w.z); d[3] = f2bf(w.w);
    }
  } else {
    for (int i = t; i < 2048; i += 256) {       // 2048 ushort8 groups
      ushort4 lo4 = ((const ushort4*)W)[2 * i];
      ushort4 hi4 = ((const ushort4*)W)[2 * i + 1];
      int base = i * 8;
      int k = base >> 8, c = base & 255;
      unsigned short* d = &Wl[k * 258 + c];
      d[0] = lo4.x; d[1] = lo4.y; d[2] = lo4.z; d[3] = lo4.w;
      d[4] = hi4.x; d[5] = hi4.y; d[6] = hi4.z; d[7] = hi4.w;
    }
  }
  __syncthreads();
  {
    int c = t;
    #pragma unroll
    for (int k8 = 0; k8 < 64; k8 += 8) {
      unsigned int p0 = (unsigned int)Wl[(k8 + 0) * 258 + c] | ((unsigned int)Wl[(k8 + 1) * 258 + c] << 16);
      unsigned int p1 = (unsigned int)Wl[(k8 + 2) * 258 + c] | ((unsigned int)Wl[(k8 + 3) * 258 + c] << 16);
      unsigned int p2 = (unsigned int)Wl[(k8 + 4) * 258 + c] | ((unsigned int)Wl[(k8 + 5) * 258 + c] << 16);
      unsigned int p3 = (unsigned int)Wl[(k8 + 6) * 258 + c] | ((unsigned int)Wl[(k8 + 7) * 258 + c] << 16);
      uint4 pk; pk.x = p0; pk.y = p1; pk.z = p2; pk.w = p3;
      *(uint4*)&WTx[c * 64 + k8] = pk;
    }
  }
  for (int idx = t; idx < 512; idx += 256) {
    int r = idx >> 6;
    int k = idx & 63;
    int h = r & 3;
    const void* av = (r >> 2) ? adst : asrc;
    float acc = 0.f;
    #pragma unroll 8
    for (int c = 0; c < 64; c++)
      acc += bf2f(Wl[k * 258 + h * 64 + c]) * loadF(av, h * 64 + c, f32);
    WTx[(256 + r) * 64 + k] = f2bf(acc);
  }
  for (int idx = t; idx < 512; idx += 256) WTx[264 * 64 + idx] = 0;
}

// ---------------- CSR build ----------------
__global__ __launch_bounds__(256) void hist_kernel(const void* __restrict__ ei, int E, int N,
                                                   const int* __restrict__ flags,
                                                   int* __restrict__ deg) {
  int e = blockIdx.x * 256 + threadIdx.x;
  if (e >= E) return;
  int is64 = flags[1];
  int d = edge_at(ei, (long long)E + e, is64);
  d = (d < 0 || d >= N) ? 0 : d;
  atomicAdd(&deg[d], 1);
}

// hierarchical scan: per-block sums -> single-wave scan of block sums -> per-block final
__global__ __launch_bounds__(256) void partial_kernel(const int* __restrict__ deg,
                                                      int* __restrict__ blocksum, int N) {
  int t = threadIdx.x;
  int idx = blockIdx.x * 256 + t;
  int v = (idx < N) ? deg[idx] : 0;
  #pragma unroll
  for (int o = 1; o < 64; o <<= 1) v += __shfl_xor(v, o);
  __shared__ int ws[4];
  if ((t & 63) == 0) ws[t >> 6] = v;
  __syncthreads();
  if (t == 0) blocksum[blockIdx.x] = ws[0] + ws[1] + ws[2] + ws[3];
}

__global__ void scan_base_kernel(const int* __restrict__ blocksum,
                                 int* __restrict__ blockbase, int B) {
  int lane = threadIdx.x;
  int base = 0;
  if (lane == 0) blockbase[0] = 0;
  for (int start = 0; start < B; start += 64) {
    int idx = start + lane;
    int v = (idx < B) ? blocksum[idx] : 0;
    int sc = v;
    #pragma unroll
    for (int o = 1; o < 64; o <<= 1) {
      int u = __shfl_up(sc, o);
      if (lane >= o) sc += u;
    }
    if (idx < B) blockbase[idx + 1] = base + sc;
    base = __shfl(base + sc, 63);
  }
}

// final: offsets[idx+1] = inclusive prefix; cursor[idx] = exclusive prefix (scatter slots)
__global__ __launch_bounds__(256) void scan_final_kernel(const int* __restrict__ deg,
                                                         const int* __restrict__ blockbase,
                                                         int* __restrict__ offsets,
                                                         int* __restrict__ cursor, int N) {
  int t = threadIdx.x;
  int lane = t & 63;
  int wid = t >> 6;
  int idx = blockIdx.x * 256 + t;
  int v = (idx < N) ? deg[idx] : 0;
  int sc = v;
  #pragma unroll
  for (int o = 1; o < 64; o <<= 1) {
    int u = __shfl_up(sc, o);
    if (lane >= o) sc += u;
  }
  __shared__ int ws[4];
  if (lane == 63) ws[wid] = sc;
  __syncthreads();
  int add = 0;
  #pragma unroll
  for (int w = 0; w < 4; w++) if (w < wid) add += ws[w];
  int incl = blockbase[blockIdx.x] + add + sc;
  if (idx < N) {
    offsets[idx + 1] = incl;
    cursor[idx] = incl - v;          // exclusive prefix = first slot for node idx
  }
  if (idx == 0) offsets[0] = 0;
}

__global__ __launch_bounds__(256) void scatter_kernel(
    const void* __restrict__ ei, int E, int N, const int* __restrict__ flags,
    int* __restrict__ cursor, int* __restrict__ csr_src) {
  int e = blockIdx.x * 256 + threadIdx.x;
  if (e >= E) return;
  int is64 = flags[1];
  int s = edge_at(ei, e, is64);
  int d = edge_at(ei, (long long)E + e, is64);
  s = (s < 0 || s >= N) ? 0 : s;
  d = (d < 0 || d >= N) ? 0 : d;
  int pos = atomicAdd(&cursor[d], 1);
  csr_src[pos] = s;
}

// ---------------- MFMA GEMM: xh = x @ W (bf16) + als/ald tile; optional fused BN ----------------
// 128 rows per block (2 row-tiles share one WTx staging). mode 1: BN+ReLU fused A-load.
__global__ __launch_bounds__(256, 3) void gemm_mfma(
    const void* __restrict__ x, const unsigned short* __restrict__ WTx,
    const int* __restrict__ flags, int mode,
    const float* __restrict__ gsum, const float* __restrict__ gsq,
    const void* __restrict__ gamma, const void* __restrict__ beta,
    unsigned short* __restrict__ xh, float* __restrict__ als, float* __restrict__ ald,
    int N) {
  __shared__ unsigned short WTs[272 * 68];    // 36 KB staged weights
  __shared__ unsigned short RP[4][16 * 68];   // per-wave repack chunk (8.5 KB)
  __shared__ float bnsc[64], bnsh[64];
  int f32 = flags[0];
  int t = threadIdx.x;
  for (int i = t; i < 272 * 8; i += 256) {
    int c = i >> 3, g = i & 7;
    uint4 v = ((const uint4*)WTx)[i];
    *(uint4*)&WTs[c * 68 + g * 8] = v;
  }
  if (mode == 1 && t < 64) {
    float mu = gsum[t] / (float)N;
    float var = fmaxf(gsq[t] / (float)N - mu * mu, 0.f);
    float sc = loadF(gamma, t, f32) * rsqrtf(var + BN_EPS);
    bnsc[t] = sc;
    bnsh[t] = loadF(beta, t, f32) - mu * sc;
  }
  __syncthreads();

  int wave = t >> 6, lane = t & 63;
  int q = lane >> 4, r16 = lane & 15;
  unsigned short* rp = RP[wave];

  #pragma unroll
  for (int rb = 0; rb < 2; rb++) {
    int m0 = blockIdx.x * 128 + rb * 64 + wave * 16;
    if (m0 >= N) break;
    int row = m0 + r16;
    int rowc = row < N ? row : N - 1;

    bf16x8 a0, a1;
    if (mode == 1) {
      const float* xp = (const float*)x + (size_t)rowc * 64 + q * 8;
      float va[8], vb[8];
      *(float4*)&va[0] = ((const float4*)xp)[0];
      *(float4*)&va[4] = ((const float4*)xp)[1];
      *(float4*)&vb[0] = ((const float4*)(xp + 32))[0];
      *(float4*)&vb[4] = ((const float4*)(xp + 32))[1];
      int k0 = q * 8;
      #pragma unroll
      for (int jj = 0; jj < 8; jj++) {
        float v = fmaxf(va[jj] * bnsc[k0 + jj] + bnsh[k0 + jj], 0.f);
        float w = fmaxf(vb[jj] * bnsc[k0 + 32 + jj] + bnsh[k0 + 32 + jj], 0.f);
        a0[jj] = (short)f2bf(v);
        a1[jj] = (short)f2bf(w);
      }
    } else if (f32) {
      const float* xp = (const float*)x + (size_t)rowc * 64 + q * 8;
      float va[8], vb[8];
      *(float4*)&va[0] = ((const float4*)xp)[0];
      *(float4*)&va[4] = ((const float4*)xp)[1];
      *(float4*)&vb[0] = ((const float4*)(xp + 32))[0];
      *(float4*)&vb[4] = ((const float4*)(xp + 32))[1];
      #pragma unroll
      for (int jj = 0; jj < 8; jj++) {
        a0[jj] = (short)f2bf(va[jj]);
        a1[jj] = (short)f2bf(vb[jj]);
      }
    } else {
      const unsigned short* xp = (const unsigned short*)x + (size_t)rowc * 64 + q * 8;
      a0 = *(const bf16x8*)xp;
      a1 = *(const bf16x8*)(xp + 32);
    }

    f32x4 acc[17];
    #pragma unroll
    for (int tt = 0; tt < 17; tt++) acc[tt] = (f32x4){0.f, 0.f, 0.f, 0.f};
    #pragma unroll
    for (int tt = 0; tt < 17; tt++) {
      int c = tt * 16 + r16;
      bf16x8 b0 = *(const bf16x8*)&WTs[c * 68 + q * 8];
      bf16x8 b1 = *(const bf16x8*)&WTs[c * 68 + 32 + q * 8];
      acc[tt] = __builtin_amdgcn_mfma_f32_16x16x32_bf16(a0, b0, acc[tt], 0, 0, 0);
      acc[tt] = __builtin_amdgcn_mfma_f32_16x16x32_bf16(a1, b1, acc[tt], 0, 0, 0);
    }

    // epilogue 1: als/ald from tile 16
    {
      int obase = m0 + q * 4;
      #pragma unroll
      for (int rr = 0; rr < 4; rr++) {
        int orow = obase + rr;
        if (orow < N) {
          if (r16 < 4) als[orow * 4 + r16] = acc[16][rr];
          else if (r16 < 8) ald[orow * 4 + (r16 - 4)] = acc[16][rr];
        }
      }
    }
    // epilogue 2: 4 chunked passes, per-wave LDS repack (wave-internal, no barrier)
    #pragma unroll
    for (int g4 = 0; g4 < 4; g4++) {
      #pragma unroll
      for (int tt2 = 0; tt2 < 4; tt2++) {
        int tile = g4 * 4 + tt2;
        #pragma unroll
        for (int rr = 0; rr < 4; rr++)
          rp[(q * 4 + rr) * 68 + tt2 * 16 + r16] = f2bf(acc[tile][rr]);
      }
      #pragma unroll
      for (int i = 0; i < 2; i++) {
        int g = i * 64 + lane;
        int r = g >> 3;
        int grp = g & 7;
        uint4 v = *(const uint4*)&rp[r * 68 + grp * 8];
        int orow = m0 + r;
        if (orow < N) ((uint4*)xh)[(size_t)orow * 32 + g4 * 8 + grp] = v;
      }
    }
  }
}

// ---------------- per-dst-node softmax aggregation ----------------
// One node per wave (one-shot frame). Half-wave edge pairing; 8 edges per unrolled iter.
__global__ __launch_bounds__(256) void agg_kernel(
    const unsigned short* __restrict__ xh,
    const float* __restrict__ als, const float* __restrict__ ald,
    const int* __restrict__ offsets, const int* __restrict__ csr_src,
    const void* __restrict__ bias, const int* __restrict__ flags,
    float* __restrict__ y, int N) {
  int lane = threadIdx.x & 63;
  int wid = threadIdx.x >> 6;
  int n = blockIdx.x * 4 + wid;
  if (n >= N) return;
  int half = lane >> 5;     // 0: even slots + self, 1: odd slots
  int hl = lane & 31;       // channels 8*hl .. 8*hl+7
  int h = hl >> 3;          // head
  const uint4* xv = (const uint4*)xh;
  float ad = ald[n * 4 + h];
  float acc0 = 0.f, acc1 = 0.f, acc2 = 0.f, acc3 = 0.f;
  float acc4 = 0.f, acc5 = 0.f, acc6 = 0.f, acc7 = 0.f;
  float dsum = 0.f;
  if (half == 0) {  // implicit self loop
    float e = als[n * 4 + h] + ad;
    e = (e > 0.f) ? e : NEG_SLOPE * e;
    float p = __expf(e);
    dsum = p;
    uint4 v = xv[(size_t)n * 32 + hl];
    acc0 = p * asf(v.x << 16); acc1 = p * asf(v.x & 0xffff0000u);
    acc2 = p * asf(v.y << 16); acc3 = p * asf(v.y & 0xffff0000u);
    acc4 = p * asf(v.z << 16); acc5 = p * asf(v.z & 0xffff0000u);
    acc6 = p * asf(v.w << 16); acc7 = p * asf(v.w & 0xffff0000u);
  }
  int beg = offsets[n], end = offsets[n + 1];
  int j = beg;
  for (; j + 8 <= end; j += 8) {
    int s0 = csr_src[j + 0 + half];
    int s1 = csr_src[j + 2 + half];
    int s2 = csr_src[j + 4 + half];
    int s3 = csr_src[j + 6 + half];
    uint4 v0 = xv[(size_t)s0 * 32 + hl];
    uint4 v1 = xv[(size_t)s1 * 32 + hl];
    uint4 v2 = xv[(size_t)s2 * 32 + hl];
    uint4 v3 = xv[(size_t)s3 * 32 + hl];
    float e0 = als[s0 * 4 + h] + ad;
    float e1 = als[s1 * 4 + h] + ad;
    float e2 = als[s2 * 4 + h] + ad;
    float e3 = als[s3 * 4 + h] + ad;
    e0 = (e0 > 0.f) ? e0 : NEG_SLOPE * e0;
    e1 = (e1 > 0.f) ? e1 : NEG_SLOPE * e1;
    e2 = (e2 > 0.f) ? e2 : NEG_SLOPE * e2;
    e3 = (e3 > 0.f) ? e3 : NEG_SLOPE * e3;
    float p0 = __expf(e0);
    float p1 = __expf(e1);
    float p2 = __expf(e2);
    float p3 = __expf(e3);
    dsum += p0 + p1 + p2 + p3;
    acc0 += p0 * asf(v0.x << 16) + p1 * asf(v1.x << 16)
          + p2 * asf(v2.x << 16) + p3 * asf(v3.x << 16);
    acc1 += p0 * asf(v0.x & 0xffff0000u) + p1 * asf(v1.x & 0xffff0000u)
          + p2 * asf(v2.x & 0xffff0000u) + p3 * asf(v3.x & 0xffff0000u);
    acc2 += p0 * asf(v0.y << 16) + p1 * asf(v1.y << 16)
          + p2 * asf(v2.y << 16) + p3 * asf(v3.y << 16);
    acc3 += p0 * asf(v0.y & 0xffff0000u) + p1 * asf(v1.y & 0xffff0000u)
          + p2 * asf(v2.y & 0xffff0000u) + p3 * asf(v3.y & 0xffff0000u);
    acc4 += p0 * asf(v0.z << 16) + p1 * asf(v1.z << 16)
          + p2 * asf(v2.z << 16) + p3 * asf(v3.z << 16);
    acc5 += p0 * asf(v0.z & 0xffff0000u) + p1 * asf(v1.z & 0xffff0000u)
          + p2 * asf(v2.z & 0xffff0000u) + p3 * asf(v3.z & 0xffff0000u);
    acc6 += p0 * asf(v0.w << 16) + p1 * asf(v1.w << 16)
          + p2 * asf(v2.w << 16) + p3 * asf(v3.w << 16);
    acc7 += p0 * asf(v0.w & 0xffff0000u) + p1 * asf(v1.w & 0xffff0000u)
          + p2 * asf(v2.w & 0xffff0000u) + p3 * asf(v3.w & 0xffff0000u);
  }
  for (; j < end; j += 2) {  // remainder: one edge per half
    int jj = j + half;
    if (jj < end) {
      int s = csr_src[jj];
      uint4 v = xv[(size_t)s * 32 + hl];
      float e = als[s * 4 + h] + ad;
      e = (e > 0.f) ? e : NEG_SLOPE * e;
      float p = __expf(e);
      dsum += p;
      acc0 += p * asf(v.x << 16); acc1 += p * asf(v.x & 0xffff0000u);
      acc2 += p * asf(v.y << 16); acc3 += p * asf(v.y & 0xffff0000u);
      acc4 += p * asf(v.z << 16); acc5 += p * asf(v.z & 0xffff0000u);
      acc6 += p * asf(v.w << 16); acc7 += p * asf(v.w & 0xffff0000u);
    }
  }
  // combine halves
  dsum += __shfl_xor(dsum, 32);
  acc0 += __shfl_xor(acc0, 32); acc1 += __shfl_xor(acc1, 32);
  acc2 += __shfl_xor(acc2, 32); acc3 += __shfl_xor(acc3, 32);
  acc4 += __shfl_xor(acc4, 32); acc5 += __shfl_xor(acc5, 32);
  acc6 += __shfl_xor(acc6, 32); acc7 += __shfl_xor(acc7, 32);
  float inv = 1.0f / dsum;
  acc0 *= inv; acc1 *= inv; acc2 *= inv; acc3 *= inv;
  acc4 *= inv; acc5 *= inv; acc6 *= inv; acc7 *= inv;
  // mean over heads: channel c lives in lanes {hl&7, +8, +16, +24}
  acc0 += __shfl_xor(acc0, 8); acc0 += __shfl_xor(acc0, 16);
  acc1 += __shfl_xor(acc1, 8); acc1 += __shfl_xor(acc1, 16);
  acc2 += __shfl_xor(acc2, 8); acc2 += __shfl_xor(acc2, 16);
  acc3 += __shfl_xor(acc3, 8); acc3 += __shfl_xor(acc3, 16);
  acc4 += __shfl_xor(acc4, 8); acc4 += __shfl_xor(acc4, 16);
  acc5 += __shfl_xor(acc5, 8); acc5 += __shfl_xor(acc5, 16);
  acc6 += __shfl_xor(acc6, 8); acc6 += __shfl_xor(acc6, 16);
  acc7 += __shfl_xor(acc7, 8); acc7 += __shfl_xor(acc7, 16);
  if (lane < 8) {
    int f32 = flags[0];
    int cb = 8 * lane;
    float4 o0, o1;
    o0.x = 0.25f * acc0 + loadF(bias, cb + 0, f32);
    o0.y = 0.25f * acc1 + loadF(bias, cb + 1, f32);
    o0.z = 0.25f * acc2 + loadF(bias, cb + 2, f32);
    o0.w = 0.25f * acc3 + loadF(bias, cb + 3, f32);
    o1.x = 0.25f * acc4 + loadF(bias, cb + 4, f32);
    o1.y = 0.25f * acc5 + loadF(bias, cb + 5, f32);
    o1.z = 0.25f * acc6 + loadF(bias, cb + 6, f32);
    o1.w = 0.25f * acc7 + loadF(bias, cb + 7, f32);
    *(float4*)(y + (size_t)n * 64 + cb) = o0;
    *(float4*)(y + (size_t)n * 64 + cb + 4) = o1;
  }
}

// ---------------- BN stats (per-channel sum / sumsq) ----------------
__global__ __launch_bounds__(256) void stats_kernel(const float* __restrict__ y,
                                                    float* __restrict__ gsum,
                                                    float* __restrict__ gsq, int N) {
  __shared__ float ls[256], lq[256];
  int t = threadIdx.x;
  int c = t & 63;
  int r0 = blockIdx.x * 4 + (t >> 6);
  float s = 0.f, q = 0.f;
  for (int r = r0; r < N; r += gridDim.x * 4) {
    float v = y[(size_t)r * 64 + c];
    s += v; q += v * v;
  }
  ls[t] = s; lq[t] = q;
  __syncthreads();
  if (t < 64) {
    s = ls[t] + ls[t + 64] + ls[t + 128] + ls[t + 192];
    q = lq[t] + lq[t + 64] + lq[t + 128] + lq[t + 192];
    atomicAdd(&gsum[c], s);
    atomicAdd(&gsq[c], q);
  }
}

// ---------------- BN apply + ReLU (final output only) ----------------
__global__ __launch_bounds__(256) void bn_kernel(
    const float* __restrict__ y, const float* __restrict__ gsum, const float* __restrict__ gsq,
    const void* __restrict__ gamma, const void* __restrict__ beta,
    const int* __restrict__ flags, float* __restrict__ out_f, int N) {
  int i = blockIdx.x * 256 + threadIdx.x;
  if (i >= N * 16) return;
  int f32 = flags[0];
  int cg = i & 15;
  float4 v = ((const float4*)y)[i];
  float4 s = ((const float4*)gsum)[cg];
  float4 q = ((const float4*)gsq)[cg];
  float inv_n = 1.0f / (float)N;
  float vv[4] = {v.x, v.y, v.z, v.w};
  float ss[4] = {s.x, s.y, s.z, s.w};
  float qq[4] = {q.x, q.y, q.z, q.w};
  float o[4];
  #pragma unroll
  for (int k = 0; k < 4; k++) {
    float g = loadF(gamma, 4 * cg + k, f32);
    float b = loadF(beta, 4 * cg + k, f32);
    float mu = ss[k] * inv_n;
    float var = fmaxf(qq[k] * inv_n - mu * mu, 0.f);
    float r = g * (vv[k] - mu) * rsqrtf(var + BN_EPS) + b;
    o[k] = r > 0.f ? r : 0.f;
  }
  float4 ov; ov.x = o[0]; ov.y = o[1]; ov.z = o[2]; ov.w = o[3];
  ((float4*)out_f)[i] = ov;
}

// ---------------- launch ----------------
extern "C" void kernel_launch(void* const* d_in, const int* in_sizes, int n_in,
                              void* d_out, int out_size, void* d_ws, size_t ws_size,
                              hipStream_t stream) {
  const void* x    = d_in[0];
  const void* ei   = d_in[1];
  const void* W0    = d_in[3];
  const void* asrc0 = d_in[4];
  const void* adst0 = d_in[5];
  const void* b0    = d_in[6];
  const void* g0    = d_in[7];
  const void* be0   = d_in[8];
  const void* W1    = d_in[9];
  const void* asrc1 = d_in[10];
  const void* adst1 = d_in[11];
  const void* b1    = d_in[12];
  const void* g1    = d_in[13];
  const void* be1   = d_in[14];

  int N = in_sizes[0] / 64;
  int E = in_sizes[1] / 2;
  int NB = (N + 255) / 256;    // scan blocks
  int NG = (N + 127) / 128;    // gemm blocks (128 rows each)
  int NA = (N + 3) / 4;        // agg blocks: one node per wave

  char* p = (char*)d_ws;
  auto alloc = [&](size_t bytes) -> char* {
    char* r = p;
    p += (bytes + 255) & ~(size_t)255;
    return r;
  };
  int* flags    = (int*)alloc(256);
  int* deg      = (int*)alloc((size_t)N * 4);
  int* cursor   = (int*)alloc((size_t)N * 4);
  int* offsets  = (int*)alloc((size_t)(N + 1) * 4);
  int* blocksum = (int*)alloc((size_t)NB * 4);
  int* blockbase= (int*)alloc((size_t)(NB + 1) * 4);
  int* csr_src  = (int*)alloc((size_t)E * 4);
  unsigned short* WTx0 = (unsigned short*)alloc(272 * 64 * 2);
  unsigned short* WTx1 = (unsigned short*)alloc(272 * 64 * 2);
  unsigned short* xh = (unsigned short*)alloc((size_t)N * 256 * 2);
  float* als    = (float*)alloc((size_t)N * 4 * 4);
  float* ald    = (float*)alloc((size_t)N * 4 * 4);
  float* y      = (float*)alloc((size_t)N * 64 * 4);
  float* gsum0  = (float*)alloc(256);
  float* gsq0   = (float*)alloc(256);
  float* gsum1  = (float*)alloc(256);
  float* gsq1   = (float*)alloc(256);

  hipMemsetAsync(deg, 0, (size_t)N * 4, stream);
  hipMemsetAsync(gsum0, 0, 1024, stream);  // gsum0..gsq1 contiguous

  wtrans_kernel<<<2, 256, 0, stream>>>((const unsigned short*)x, (const int*)ei,
                                       W0, asrc0, adst0, W1, asrc1, adst1, flags, WTx0, WTx1);

  hist_kernel<<<(E + 255) / 256, 256, 0, stream>>>(ei, E, N, flags, deg);
  partial_kernel<<<NB, 256, 0, stream>>>(deg, blocksum, N);
  scan_base_kernel<<<1, 64, 0, stream>>>(blocksum, blockbase, NB);
  scan_final_kernel<<<NB, 256, 0, stream>>>(deg, blockbase, offsets, cursor, N);
  scatter_kernel<<<(E + 255) / 256, 256, 0, stream>>>(ei, E, N, flags, cursor, csr_src);

  float* out_x = (float*)d_out;                    // output 0: final, fp32
  float* out_saved = out_x + (size_t)N * 64;       // output 1: layer-2 pre-BN, fp32

  // ---- layer 0 ----
  gemm_mfma<<<NG, 256, 0, stream>>>(x, WTx0, flags, 0, (const float*)nullptr,
                                    (const float*)nullptr, nullptr, nullptr,
                                    xh, als, ald, N);
  agg_kernel<<<NA, 256, 0, stream>>>(xh, als, ald, offsets, csr_src, b0, flags, y, N);
  stats_kernel<<<250, 256, 0, stream>>>(y, gsum0, gsq0, N);
  // ---- layer 1 (BN of layer 0 fused into gemm A-load) ----
  gemm_mfma<<<NG, 256, 0, stream>>>(y, WTx1, flags, 1, gsum0, gsq0, g0, be0,
                                    xh, als, ald, N);
  agg_kernel<<<NA, 256, 0, stream>>>(xh, als, ald, offsets, csr_src, b1, flags, out_saved, N);
  stats_kernel<<<250, 256, 0, stream>>>(out_saved, gsum1, gsq1, N);
  bn_kernel<<<(N * 16 + 255) / 256, 256, 0, stream>>>(out_saved, gsum1, gsq1, g1, be1,
                                                      flags, out_x, N);
}